// Round 13
// baseline (104.117 us; speedup 1.0000x reference)
//
#include <hip/hip_runtime.h>
#include <hip/hip_bf16.h>
#include <cstdint>
#include <cstddef>

using bf16 = __hip_bfloat16;
typedef __attribute__((ext_vector_type(8))) short bf16x8v;
typedef __attribute__((ext_vector_type(4))) float f32x4v;
typedef __attribute__((ext_vector_type(16))) float f32x16v;
typedef __attribute__((ext_vector_type(4))) int i32x4v;

__device__ __forceinline__ f32x4v mfma16x16x32(bf16x8v a, bf16x8v b, f32x4v c) {
  return __builtin_amdgcn_mfma_f32_16x16x32_bf16(a, b, c, 0, 0, 0);
}
__device__ __forceinline__ f32x16v mfma32x32x16(bf16x8v a, bf16x8v b, f32x16v c) {
  return __builtin_amdgcn_mfma_f32_32x32x16_bf16(a, b, c, 0, 0, 0);
}

__device__ __forceinline__ void lds_async16(const void* g, void* l) {
  __builtin_amdgcn_global_load_lds(
      (__attribute__((address_space(1))) void*)g,
      (__attribute__((address_space(3))) void*)l, 16, 0, 0);
}

__device__ __forceinline__ unsigned short f2bf_bits(float f) {
  union { bf16 h; unsigned short u; } cv;
  cv.h = __float2bfloat16(f);
  return cv.u;
}
__device__ __forceinline__ uint32_t pk_bf2(float a, float b) {
  return (uint32_t)f2bf_bits(a) | ((uint32_t)f2bf_bits(b) << 16);
}

// 1/sqrt(64) * log2(e), folded into Q at the QKV-GEMM epilogue
#define QSC 0.18033688011111793f

// ---------------- fused prep: convert_x + transpose_w + bias, one dispatch ----
__global__ void prep_k(const float* __restrict__ x,
                       const float* __restrict__ Wq, const float* __restrict__ Wk,
                       const float* __restrict__ Wv, const float* __restrict__ Wo,
                       const float* __restrict__ bq, const float* __restrict__ bk,
                       const float* __restrict__ bv,
                       bf16* __restrict__ xb, bf16* __restrict__ wcat,
                       bf16* __restrict__ wot, float* __restrict__ bcat)
{
  __shared__ float tile[64][65];
  const int bid = blockIdx.x;
  if (bid < 4096) {
    const int i = bid * 256 + threadIdx.x;
    const float4 v = reinterpret_cast<const float4*>(x)[i];
    ushort4 o;
    o.x = f2bf_bits(v.x); o.y = f2bf_bits(v.y);
    o.z = f2bf_bits(v.z); o.w = f2bf_bits(v.w);
    reinterpret_cast<ushort4*>(xb)[i] = o;
  } else if (bid < 5120) {
    const int b2 = bid - 4096;
    const int mat = b2 >> 8;
    const float* W = (mat == 0) ? Wq : (mat == 1) ? Wk : (mat == 2) ? Wv : Wo;
    bf16* dst = (mat < 3) ? (wcat + (size_t)mat * 1024 * 1024) : wot;
    const int n0 = ((b2 >> 4) & 15) * 64, k0 = (b2 & 15) * 64;
    const int tr = threadIdx.x >> 6, tc = threadIdx.x & 63;
#pragma unroll
    for (int it = 0; it < 16; ++it)
      tile[it * 4 + tr][tc] = W[(size_t)(k0 + it * 4 + tr) * 1024 + n0 + tc];
    __syncthreads();
    // vectorized transposed store: 4 x ushort4 per thread (G13)
#pragma unroll
    for (int i = 0; i < 4; ++i) {
      const int idx = i * 256 + threadIdx.x;       // 0..1023
      const int n = idx >> 4, c = idx & 15;        // n-row, k-granule of 4
      ushort4 o;
      o.x = f2bf_bits(tile[4 * c + 0][n]);
      o.y = f2bf_bits(tile[4 * c + 1][n]);
      o.z = f2bf_bits(tile[4 * c + 2][n]);
      o.w = f2bf_bits(tile[4 * c + 3][n]);
      *reinterpret_cast<ushort4*>(dst + (size_t)(n0 + n) * 1024 + k0 + 4 * c) = o;
    }
  } else {
    const int i = (bid - 5120) * 256 + threadIdx.x;
    if (i < 3072)
      bcat[i] = (i < 1024) ? bq[i] : (i < 2048) ? bk[i - 1024] : bv[i - 2048];
  }
}

// ---------------- GEMM (R10 verbatim — FROZEN) --------------------------------
template <int EPI>
__global__ __launch_bounds__(256, 3) void gemm_k(
    const bf16* __restrict__ A, const bf16* __restrict__ Bt,
    const float* __restrict__ bias,
    bf16* __restrict__ qb, bf16* __restrict__ kb, bf16* __restrict__ vtb,
    float* __restrict__ outf)
{
  constexpr int K = 1024;
  __shared__ bf16 smem[16384];               // 32 KB = 2 bufs x 16 KB
  const int t = threadIdx.x;
  const int lane = t & 63, w = t >> 6;
  const int g = lane >> 4, r = lane & 15;
  const int wr = w >> 1, wc = w & 1;
  const int m0 = blockIdx.x * 128, n0 = blockIdx.y * 128;

  const int srow = t >> 2;
  const int scol = ((lane & 3) ^ g) << 3;
  const bf16* aS0 = A + (size_t)(m0 + srow) * K + scol;
  const bf16* aS1 = A + (size_t)(m0 + 64 + srow) * K + scol;
  const bf16* bS0 = Bt + (size_t)(n0 + srow) * K + scol;
  const bf16* bS1 = Bt + (size_t)(n0 + 64 + srow) * K + scol;

  f32x4v acc[4][4] = {};

  auto STAGE = [&](int kt, int buf) {
    const int ko = kt * 32;
    char* d0 = (char*)smem + buf * 16384 + w * 1024;
    lds_async16(aS0 + ko, d0);
    lds_async16(aS1 + ko, d0 + 4096);
    lds_async16(bS0 + ko, d0 + 8192);
    lds_async16(bS1 + ko, d0 + 12288);
  };

  const int csw = (g ^ ((r >> 2) & 3)) << 4;

  STAGE(0, 0);
  asm volatile("s_waitcnt vmcnt(0)" ::: "memory");
  __builtin_amdgcn_s_barrier();

  for (int kt = 0; kt < 32; ++kt) {
    if (kt < 31) STAGE(kt + 1, (kt + 1) & 1);

    const char* buf = (const char*)smem + (kt & 1) * 16384;
    bf16x8v af[4], bfr[4];
#pragma unroll
    for (int m = 0; m < 4; ++m)
      af[m] = *reinterpret_cast<const bf16x8v*>(buf + (wr * 64 + m * 16 + r) * 64 + csw);
#pragma unroll
    for (int n = 0; n < 4; ++n)
      bfr[n] = *reinterpret_cast<const bf16x8v*>(buf + 8192 + (wc * 64 + n * 16 + r) * 64 + csw);
#pragma unroll
    for (int m = 0; m < 4; ++m)
#pragma unroll
      for (int n = 0; n < 4; ++n)
        acc[m][n] = mfma16x16x32(af[m], bfr[n], acc[m][n]);

    if (kt < 31) asm volatile("s_waitcnt vmcnt(0)" ::: "memory");
    __builtin_amdgcn_s_barrier();
  }

  if (EPI == 0) {
    const int gcol0 = n0 + wc * 64;
    const int mat = gcol0 >> 10;
    const int hh = (gcol0 & 1023) >> 6;
    const int s0 = m0 + wr * 64;
    const int b_ = s0 >> 11, sb = s0 & 2047;
    const size_t bh = (size_t)(b_ * 16 + hh);
    unsigned short* ep = (unsigned short*)smem + w * 4096;

#pragma unroll
    for (int n = 0; n < 4; ++n) {
      const int dkl = n * 16 + r;
      const float bv_ = bias[gcol0 + dkl];
#pragma unroll
      for (int m = 0; m < 4; ++m) {
#pragma unroll
        for (int v = 0; v < 4; ++v) {
          const int sl = m * 16 + g * 4 + v;
          const float val = acc[m][n][v] + bv_;
          if (mat == 0)      ep[sl * 64 + dkl] = f2bf_bits(val * QSC);
          else if (mat == 1) ep[sl * 64 + dkl] = f2bf_bits(val);
          else               ep[dkl * 64 + sl] = f2bf_bits(val);
        }
      }
    }
#pragma unroll
    for (int i = 0; i < 8; ++i) {
      const int chunk = i * 64 + lane;
      const int rw = chunk >> 3;
      const int off = (chunk & 7) * 8;
      const bf16x8v vv = *reinterpret_cast<const bf16x8v*>(ep + rw * 64 + off);
      if (mat == 0)
        *reinterpret_cast<bf16x8v*>(qb + (bh * 2048 + sb + rw) * 64 + off) = vv;
      else if (mat == 1)
        *reinterpret_cast<bf16x8v*>(kb + (bh * 2048 + sb + rw) * 64 + off) = vv;
      else
        *reinterpret_cast<bf16x8v*>(vtb + (bh * 64 + rw) * 2048 + sb + off) = vv;
    }
  } else {
#pragma unroll
    for (int n = 0; n < 4; ++n) {
      const int gcol = n0 + wc * 64 + n * 16 + r;
      const float bv_ = bias[gcol];
#pragma unroll
      for (int m = 0; m < 4; ++m) {
#pragma unroll
        for (int v = 0; v < 4; ++v) {
          const int grow = m0 + wr * 64 + m * 16 + g * 4 + v;
          outf[(size_t)grow * 1024 + gcol] = acc[m][n][v] + bv_;
        }
      }
    }
  }
}

// ---------------- sliding-window attention: 4 waves/q-tile, additive merge ----
// No-max softmax => partials over disjoint key ranges are ADDITIVE.
// Block = 256 thr (4 waves), same 32-row q-tile, j-range quartered
// -> ~7 waves/SIMD (VGPR-capped) vs 4 -> deeper latency hiding.
__global__ __launch_bounds__(256) void attn_k(
    const bf16* __restrict__ qb, const bf16* __restrict__ kb_,
    const bf16* __restrict__ vtb, bf16* __restrict__ aout)
{
  constexpr int S = 2048;
  const int tid = threadIdx.x;
  const int wid = tid >> 6;
  const int lane = tid & 63;
  const int hi = lane >> 5, l31 = lane & 31;
  const int d_ = blockIdx.x;
  const int xcd = d_ & 7, slot = d_ >> 3;
  const int bh_i = xcd * 4 + (slot >> 6);
  const int q0 = (slot & 63) * 32;
  const int b = bh_i >> 4, h = bh_i & 15;
  const size_t bh = (size_t)b * 16 + h;
  const bf16* qp = qb + bh * (size_t)(S * 64);
  const bf16* kp = kb_ + bh * (size_t)(S * 64);
  const bf16* vp = vtb + bh * (size_t)(64 * S);

  __shared__ float msum[3][64][33];   // 25.3 KB merge buffer

  bf16x8v qf[4];
#pragma unroll
  for (int i = 0; i < 4; ++i)
    qf[i] = *reinterpret_cast<const bf16x8v*>(&qp[(size_t)(q0 + l31) * 64 + i * 16 + hi * 8]);

  f32x16v o0 = {}, o1 = {};
  float lrun = 0.f;

  const int jlo = (q0 >= 256) ? (q0 - 256) : 0;
  const int jend = (q0 + 256 <= S - 32) ? (q0 + 256) : (S - 32);
  const int nIter = ((jend - jlo) >> 5) + 1;
  // quarter split: wave w gets base + (w<rem), start offset w*base + min(w,rem)
  const int base_ = nIter >> 2, rem = nIter & 3;
  const int myN = base_ + (wid < rem ? 1 : 0);
  const int jlo_w = jlo + 32 * (wid * base_ + (wid < rem ? wid : rem));

  auto LDK = [&](int j, bf16x8v* kf) {
    const bf16* p0 = kp + (size_t)(j + l31) * 64 + hi * 8;
#pragma unroll
    for (int i = 0; i < 4; ++i)
      kf[i] = *reinterpret_cast<const bf16x8v*>(p0 + i * 16);
  };
  auto LDV = [&](int j, bf16x8v* vf) {
#pragma unroll
    for (int db = 0; db < 2; ++db)
#pragma unroll
      for (int kk = 0; kk < 2; ++kk)
        vf[db * 2 + kk] = *reinterpret_cast<const bf16x8v*>(
            &vp[(size_t)(db * 32 + l31) * S + j + kk * 16 + hi * 8]);
  };

  auto STEP = [&](int idx, bf16x8v* kc, bf16x8v* vc, bf16x8v* kn, bf16x8v* vn) {
    const int j = jlo_w + idx * 32;
    if (idx + 1 < myN) { LDK(j + 32, kn); LDV(j + 32, vn); }

    f32x16v s = {};
#pragma unroll
    for (int i = 0; i < 4; ++i) s = mfma32x32x16(kc[i], qf[i], s);

    float p[16];
    const bool needMask = ((q0 + 31 - j) > 256) || ((j + 31 - q0) > 256);
    if (needMask) {
      const int base2 = l31 - 4 * hi + (q0 - j) + 256;
#pragma unroll
      for (int tt = 0; tt < 4; ++tt)
#pragma unroll
        for (int e = 0; e < 4; ++e) {
          const int kk_ = 8 * tt + e;
          const float ev = __builtin_amdgcn_exp2f(s[4 * tt + e]);
          p[4 * tt + e] = ((unsigned)(base2 - kk_) <= 512u) ? ev : 0.f;
        }
    } else {
#pragma unroll
      for (int i = 0; i < 16; ++i) p[i] = __builtin_amdgcn_exp2f(s[i]);
    }
    lrun += (((p[0] + p[1]) + (p[2] + p[3])) + ((p[4] + p[5]) + (p[6] + p[7]))) +
            (((p[8] + p[9]) + (p[10] + p[11])) + ((p[12] + p[13]) + (p[14] + p[15])));

    uint32_t W00 = pk_bf2(p[0],  p[1]),  W01 = pk_bf2(p[2],  p[3]);
    uint32_t W10 = pk_bf2(p[4],  p[5]),  W11 = pk_bf2(p[6],  p[7]);
    uint32_t W20 = pk_bf2(p[8],  p[9]),  W21 = pk_bf2(p[10], p[11]);
    uint32_t W30 = pk_bf2(p[12], p[13]), W31 = pk_bf2(p[14], p[15]);
    asm volatile("v_permlane32_swap_b32 %0, %1" : "+v"(W00), "+v"(W10));
    asm volatile("v_permlane32_swap_b32 %0, %1" : "+v"(W01), "+v"(W11));
    asm volatile("v_permlane32_swap_b32 %0, %1" : "+v"(W20), "+v"(W30));
    asm volatile("v_permlane32_swap_b32 %0, %1" : "+v"(W21), "+v"(W31));
    union { i32x4v i; bf16x8v hv; } c0, c1;
    c0.i = (i32x4v){(int)W00, (int)W01, (int)W10, (int)W11};
    c1.i = (i32x4v){(int)W20, (int)W21, (int)W30, (int)W31};
    o0 = mfma32x32x16(vc[0], c0.hv, o0);
    o0 = mfma32x32x16(vc[1], c1.hv, o0);
    o1 = mfma32x32x16(vc[2], c0.hv, o1);
    o1 = mfma32x32x16(vc[3], c1.hv, o1);
  };

  bf16x8v ka[4], va[4], kn2[4], vn2[4];
  LDK(jlo_w, ka); LDV(jlo_w, va);
  int it = 0;
  while (it + 2 <= myN) {
    STEP(it, ka, va, kn2, vn2);
    STEP(it + 1, kn2, vn2, ka, va);
    it += 2;
  }
  if (it < myN) STEP(it, ka, va, kn2, vn2);

  // additive merge: waves 1..3 -> LDS, wave0 accumulates and writes out
  if (wid != 0) {
    float* mp = &msum[wid - 1][lane][0];
#pragma unroll
    for (int i = 0; i < 16; ++i) { mp[i] = o0[i]; mp[16 + i] = o1[i]; }
    mp[32] = lrun;
  }
  __syncthreads();
  if (wid == 0) {
#pragma unroll
    for (int wv = 0; wv < 3; ++wv) {
      const float* mp = &msum[wv][lane][0];
#pragma unroll
      for (int i = 0; i < 16; ++i) { o0[i] += mp[i]; o1[i] += mp[16 + i]; }
      lrun += mp[32];
    }
    lrun += __shfl_xor(lrun, 32);
    const float inv = 1.0f / lrun;

    const size_t ob = ((size_t)b * S + q0 + l31) * 1024 + h * 64 + hi * 4;
#pragma unroll
    for (int tt = 0; tt < 4; ++tt) {
      uint2 u;
      u.x = pk_bf2(o0[4 * tt] * inv, o0[4 * tt + 1] * inv);
      u.y = pk_bf2(o0[4 * tt + 2] * inv, o0[4 * tt + 3] * inv);
      *reinterpret_cast<uint2*>(&aout[ob + 8 * tt]) = u;
      uint2 v2;
      v2.x = pk_bf2(o1[4 * tt] * inv, o1[4 * tt + 1] * inv);
      v2.y = pk_bf2(o1[4 * tt + 2] * inv, o1[4 * tt + 3] * inv);
      *reinterpret_cast<uint2*>(&aout[ob + 32 + 8 * tt]) = v2;
    }
  }
}

// ---------------- launch ----------------
extern "C" void kernel_launch(void* const* d_in, const int* in_sizes, int n_in,
                              void* d_out, int out_size, void* d_ws, size_t ws_size,
                              hipStream_t stream) {
  (void)in_sizes; (void)n_in; (void)out_size; (void)ws_size;
  const float* x  = (const float*)d_in[0];
  const float* Wq = (const float*)d_in[1];
  const float* bq = (const float*)d_in[2];
  const float* Wk = (const float*)d_in[3];
  const float* bk = (const float*)d_in[4];
  const float* Wv = (const float*)d_in[5];
  const float* bv = (const float*)d_in[6];
  const float* Wo = (const float*)d_in[7];
  const float* bo = (const float*)d_in[8];
  float* out = (float*)d_out;

  char* ws = (char*)d_ws;
  bf16*  xb    = (bf16*)(ws);                    // 8 MB  [4096][1024]
  bf16*  wcat  = (bf16*)(ws + 8388608);          // 6 MB  [3072][1024]
  bf16*  wot   = (bf16*)(ws + 14680064);         // 2 MB  [1024][1024]
  bf16*  qbuf  = (bf16*)(ws + 16777216);         // 8 MB  [B,H,S,64] (pre-scaled)
  bf16*  kbuf  = (bf16*)(ws + 25165824);         // 8 MB  [B,H,S,64]
  bf16*  vtbuf = (bf16*)(ws + 33554432);         // 8 MB  [B,H,64,S]
  bf16*  aoutb = (bf16*)(ws + 41943040);         // 8 MB  [B,S,1024]
  float* bcat  = (float*)(ws + 50331648);        // 12 KB [3072]

  prep_k<<<5132, 256, 0, stream>>>(x, Wq, Wk, Wv, Wo, bq, bk, bv,
                                   xb, wcat, wot, bcat);

  gemm_k<0><<<dim3(32, 24), 256, 0, stream>>>(xb, wcat, bcat, qbuf, kbuf, vtbuf, nullptr);
  attn_k<<<2048, 256, 0, stream>>>(qbuf, kbuf, vtbuf, aoutb);
  gemm_k<1><<<dim3(32, 8), 256, 0, stream>>>(aoutb, wot, bo, nullptr, nullptr, nullptr, out);
}

// Round 14
// 101.868 us; speedup vs baseline: 1.0221x; 1.0221x over previous
//
#include <hip/hip_runtime.h>
#include <hip/hip_bf16.h>
#include <cstdint>
#include <cstddef>

using bf16 = __hip_bfloat16;
typedef __attribute__((ext_vector_type(8))) short bf16x8v;
typedef __attribute__((ext_vector_type(4))) float f32x4v;
typedef __attribute__((ext_vector_type(16))) float f32x16v;
typedef __attribute__((ext_vector_type(4))) int i32x4v;

__device__ __forceinline__ f32x4v mfma16x16x32(bf16x8v a, bf16x8v b, f32x4v c) {
  return __builtin_amdgcn_mfma_f32_16x16x32_bf16(a, b, c, 0, 0, 0);
}
__device__ __forceinline__ f32x16v mfma32x32x16(bf16x8v a, bf16x8v b, f32x16v c) {
  return __builtin_amdgcn_mfma_f32_32x32x16_bf16(a, b, c, 0, 0, 0);
}

__device__ __forceinline__ void lds_async16(const void* g, void* l) {
  __builtin_amdgcn_global_load_lds(
      (__attribute__((address_space(1))) void*)g,
      (__attribute__((address_space(3))) void*)l, 16, 0, 0);
}

__device__ __forceinline__ unsigned short f2bf_bits(float f) {
  union { bf16 h; unsigned short u; } cv;
  cv.h = __float2bfloat16(f);
  return cv.u;
}
__device__ __forceinline__ uint32_t pk_bf2(float a, float b) {
  return (uint32_t)f2bf_bits(a) | ((uint32_t)f2bf_bits(b) << 16);
}

// 1/sqrt(64) * log2(e), folded into Q at the QKV-GEMM epilogue
#define QSC 0.18033688011111793f

// ---------------- fused prep: convert_x + transpose_w + bias, one dispatch ----
__global__ void prep_k(const float* __restrict__ x,
                       const float* __restrict__ Wq, const float* __restrict__ Wk,
                       const float* __restrict__ Wv, const float* __restrict__ Wo,
                       const float* __restrict__ bq, const float* __restrict__ bk,
                       const float* __restrict__ bv,
                       bf16* __restrict__ xb, bf16* __restrict__ wcat,
                       bf16* __restrict__ wot, float* __restrict__ bcat)
{
  __shared__ float tile[64][65];
  const int bid = blockIdx.x;
  if (bid < 4096) {
    const int i = bid * 256 + threadIdx.x;
    const float4 v = reinterpret_cast<const float4*>(x)[i];
    ushort4 o;
    o.x = f2bf_bits(v.x); o.y = f2bf_bits(v.y);
    o.z = f2bf_bits(v.z); o.w = f2bf_bits(v.w);
    reinterpret_cast<ushort4*>(xb)[i] = o;
  } else if (bid < 5120) {
    const int b2 = bid - 4096;
    const int mat = b2 >> 8;
    const float* W = (mat == 0) ? Wq : (mat == 1) ? Wk : (mat == 2) ? Wv : Wo;
    bf16* dst = (mat < 3) ? (wcat + (size_t)mat * 1024 * 1024) : wot;
    const int n0 = ((b2 >> 4) & 15) * 64, k0 = (b2 & 15) * 64;
    const int tr = threadIdx.x >> 6, tc = threadIdx.x & 63;
#pragma unroll
    for (int it = 0; it < 16; ++it)
      tile[it * 4 + tr][tc] = W[(size_t)(k0 + it * 4 + tr) * 1024 + n0 + tc];
    __syncthreads();
    // vectorized transposed store: 4 x ushort4 per thread (G13)
#pragma unroll
    for (int i = 0; i < 4; ++i) {
      const int idx = i * 256 + threadIdx.x;       // 0..1023
      const int n = idx >> 4, c = idx & 15;        // n-row, k-granule of 4
      ushort4 o;
      o.x = f2bf_bits(tile[4 * c + 0][n]);
      o.y = f2bf_bits(tile[4 * c + 1][n]);
      o.z = f2bf_bits(tile[4 * c + 2][n]);
      o.w = f2bf_bits(tile[4 * c + 3][n]);
      *reinterpret_cast<ushort4*>(dst + (size_t)(n0 + n) * 1024 + k0 + 4 * c) = o;
    }
  } else {
    const int i = (bid - 5120) * 256 + threadIdx.x;
    if (i < 3072)
      bcat[i] = (i < 1024) ? bq[i] : (i < 2048) ? bk[i - 1024] : bv[i - 2048];
  }
}

// ---------------- GEMM (R10 verbatim — FROZEN) --------------------------------
template <int EPI>
__global__ __launch_bounds__(256, 3) void gemm_k(
    const bf16* __restrict__ A, const bf16* __restrict__ Bt,
    const float* __restrict__ bias,
    bf16* __restrict__ qb, bf16* __restrict__ kb, bf16* __restrict__ vtb,
    float* __restrict__ outf)
{
  constexpr int K = 1024;
  __shared__ bf16 smem[16384];               // 32 KB = 2 bufs x 16 KB
  const int t = threadIdx.x;
  const int lane = t & 63, w = t >> 6;
  const int g = lane >> 4, r = lane & 15;
  const int wr = w >> 1, wc = w & 1;
  const int m0 = blockIdx.x * 128, n0 = blockIdx.y * 128;

  const int srow = t >> 2;
  const int scol = ((lane & 3) ^ g) << 3;
  const bf16* aS0 = A + (size_t)(m0 + srow) * K + scol;
  const bf16* aS1 = A + (size_t)(m0 + 64 + srow) * K + scol;
  const bf16* bS0 = Bt + (size_t)(n0 + srow) * K + scol;
  const bf16* bS1 = Bt + (size_t)(n0 + 64 + srow) * K + scol;

  f32x4v acc[4][4] = {};

  auto STAGE = [&](int kt, int buf) {
    const int ko = kt * 32;
    char* d0 = (char*)smem + buf * 16384 + w * 1024;
    lds_async16(aS0 + ko, d0);
    lds_async16(aS1 + ko, d0 + 4096);
    lds_async16(bS0 + ko, d0 + 8192);
    lds_async16(bS1 + ko, d0 + 12288);
  };

  const int csw = (g ^ ((r >> 2) & 3)) << 4;

  STAGE(0, 0);
  asm volatile("s_waitcnt vmcnt(0)" ::: "memory");
  __builtin_amdgcn_s_barrier();

  for (int kt = 0; kt < 32; ++kt) {
    if (kt < 31) STAGE(kt + 1, (kt + 1) & 1);

    const char* buf = (const char*)smem + (kt & 1) * 16384;
    bf16x8v af[4], bfr[4];
#pragma unroll
    for (int m = 0; m < 4; ++m)
      af[m] = *reinterpret_cast<const bf16x8v*>(buf + (wr * 64 + m * 16 + r) * 64 + csw);
#pragma unroll
    for (int n = 0; n < 4; ++n)
      bfr[n] = *reinterpret_cast<const bf16x8v*>(buf + 8192 + (wc * 64 + n * 16 + r) * 64 + csw);
#pragma unroll
    for (int m = 0; m < 4; ++m)
#pragma unroll
      for (int n = 0; n < 4; ++n)
        acc[m][n] = mfma16x16x32(af[m], bfr[n], acc[m][n]);

    if (kt < 31) asm volatile("s_waitcnt vmcnt(0)" ::: "memory");
    __builtin_amdgcn_s_barrier();
  }

  if (EPI == 0) {
    const int gcol0 = n0 + wc * 64;
    const int mat = gcol0 >> 10;
    const int hh = (gcol0 & 1023) >> 6;
    const int s0 = m0 + wr * 64;
    const int b_ = s0 >> 11, sb = s0 & 2047;
    const size_t bh = (size_t)(b_ * 16 + hh);
    unsigned short* ep = (unsigned short*)smem + w * 4096;

#pragma unroll
    for (int n = 0; n < 4; ++n) {
      const int dkl = n * 16 + r;
      const float bv_ = bias[gcol0 + dkl];
#pragma unroll
      for (int m = 0; m < 4; ++m) {
#pragma unroll
        for (int v = 0; v < 4; ++v) {
          const int sl = m * 16 + g * 4 + v;
          const float val = acc[m][n][v] + bv_;
          if (mat == 0)      ep[sl * 64 + dkl] = f2bf_bits(val * QSC);
          else if (mat == 1) ep[sl * 64 + dkl] = f2bf_bits(val);
          else               ep[dkl * 64 + sl] = f2bf_bits(val);
        }
      }
    }
#pragma unroll
    for (int i = 0; i < 8; ++i) {
      const int chunk = i * 64 + lane;
      const int rw = chunk >> 3;
      const int off = (chunk & 7) * 8;
      const bf16x8v vv = *reinterpret_cast<const bf16x8v*>(ep + rw * 64 + off);
      if (mat == 0)
        *reinterpret_cast<bf16x8v*>(qb + (bh * 2048 + sb + rw) * 64 + off) = vv;
      else if (mat == 1)
        *reinterpret_cast<bf16x8v*>(kb + (bh * 2048 + sb + rw) * 64 + off) = vv;
      else
        *reinterpret_cast<bf16x8v*>(vtb + (bh * 64 + rw) * 2048 + sb + off) = vv;
    }
  } else {
#pragma unroll
    for (int n = 0; n < 4; ++n) {
      const int gcol = n0 + wc * 64 + n * 16 + r;
      const float bv_ = bias[gcol];
#pragma unroll
      for (int m = 0; m < 4; ++m) {
#pragma unroll
        for (int v = 0; v < 4; ++v) {
          const int grow = m0 + wr * 64 + m * 16 + g * 4 + v;
          outf[(size_t)grow * 1024 + gcol] = acc[m][n][v] + bv_;
        }
      }
    }
  }
}

// ---------------- sliding-window attention: 2 waves/q-tile (R12 optimum) ------
// No-max softmax => partials over disjoint key ranges are ADDITIVE:
// o_tot = o_w0 + o_w1, l_tot = l_w0 + l_w1. Block = 128 thr (2 waves),
// same 32-row q-tile, j-range halved -> 4 waves/SIMD. Measured best (R12).
__global__ __launch_bounds__(128) void attn_k(
    const bf16* __restrict__ qb, const bf16* __restrict__ kb_,
    const bf16* __restrict__ vtb, bf16* __restrict__ aout)
{
  constexpr int S = 2048;
  const int tid = threadIdx.x;
  const int wid = tid >> 6;
  const int lane = tid & 63;
  const int hi = lane >> 5, l31 = lane & 31;
  const int d_ = blockIdx.x;
  const int xcd = d_ & 7, slot = d_ >> 3;
  const int bh_i = xcd * 4 + (slot >> 6);
  const int q0 = (slot & 63) * 32;
  const int b = bh_i >> 4, h = bh_i & 15;
  const size_t bh = (size_t)b * 16 + h;
  const bf16* qp = qb + bh * (size_t)(S * 64);
  const bf16* kp = kb_ + bh * (size_t)(S * 64);
  const bf16* vp = vtb + bh * (size_t)(64 * S);

  __shared__ float msum[64 * 33];   // 8.25 KB merge buffer (stride 33)

  bf16x8v qf[4];
#pragma unroll
  for (int i = 0; i < 4; ++i)
    qf[i] = *reinterpret_cast<const bf16x8v*>(&qp[(size_t)(q0 + l31) * 64 + i * 16 + hi * 8]);

  f32x16v o0 = {}, o1 = {};
  float lrun = 0.f;

  const int jlo = (q0 >= 256) ? (q0 - 256) : 0;
  const int jend = (q0 + 256 <= S - 32) ? (q0 + 256) : (S - 32);
  const int nIter = ((jend - jlo) >> 5) + 1;
  const int h_ = (nIter + 1) >> 1;                 // wave0: h_, wave1: nIter-h_
  const int myN = wid ? (nIter - h_) : h_;
  const int jlo_w = jlo + (wid ? h_ * 32 : 0);

  auto LDK = [&](int j, bf16x8v* kf) {
    const bf16* p0 = kp + (size_t)(j + l31) * 64 + hi * 8;
#pragma unroll
    for (int i = 0; i < 4; ++i)
      kf[i] = *reinterpret_cast<const bf16x8v*>(p0 + i * 16);
  };
  auto LDV = [&](int j, bf16x8v* vf) {
#pragma unroll
    for (int db = 0; db < 2; ++db)
#pragma unroll
      for (int kk = 0; kk < 2; ++kk)
        vf[db * 2 + kk] = *reinterpret_cast<const bf16x8v*>(
            &vp[(size_t)(db * 32 + l31) * S + j + kk * 16 + hi * 8]);
  };

  auto STEP = [&](int idx, bf16x8v* kc, bf16x8v* vc, bf16x8v* kn, bf16x8v* vn) {
    const int j = jlo_w + idx * 32;
    if (idx + 1 < myN) { LDK(j + 32, kn); LDV(j + 32, vn); }

    f32x16v s = {};
#pragma unroll
    for (int i = 0; i < 4; ++i) s = mfma32x32x16(kc[i], qf[i], s);

    float p[16];
    const bool needMask = ((q0 + 31 - j) > 256) || ((j + 31 - q0) > 256);
    if (needMask) {
      const int base = l31 - 4 * hi + (q0 - j) + 256;
#pragma unroll
      for (int tt = 0; tt < 4; ++tt)
#pragma unroll
        for (int e = 0; e < 4; ++e) {
          const int kk_ = 8 * tt + e;
          const float ev = __builtin_amdgcn_exp2f(s[4 * tt + e]);
          p[4 * tt + e] = ((unsigned)(base - kk_) <= 512u) ? ev : 0.f;
        }
    } else {
#pragma unroll
      for (int i = 0; i < 16; ++i) p[i] = __builtin_amdgcn_exp2f(s[i]);
    }
    lrun += (((p[0] + p[1]) + (p[2] + p[3])) + ((p[4] + p[5]) + (p[6] + p[7]))) +
            (((p[8] + p[9]) + (p[10] + p[11])) + ((p[12] + p[13]) + (p[14] + p[15])));

    uint32_t W00 = pk_bf2(p[0],  p[1]),  W01 = pk_bf2(p[2],  p[3]);
    uint32_t W10 = pk_bf2(p[4],  p[5]),  W11 = pk_bf2(p[6],  p[7]);
    uint32_t W20 = pk_bf2(p[8],  p[9]),  W21 = pk_bf2(p[10], p[11]);
    uint32_t W30 = pk_bf2(p[12], p[13]), W31 = pk_bf2(p[14], p[15]);
    asm volatile("v_permlane32_swap_b32 %0, %1" : "+v"(W00), "+v"(W10));
    asm volatile("v_permlane32_swap_b32 %0, %1" : "+v"(W01), "+v"(W11));
    asm volatile("v_permlane32_swap_b32 %0, %1" : "+v"(W20), "+v"(W30));
    asm volatile("v_permlane32_swap_b32 %0, %1" : "+v"(W21), "+v"(W31));
    union { i32x4v i; bf16x8v hv; } c0, c1;
    c0.i = (i32x4v){(int)W00, (int)W01, (int)W10, (int)W11};
    c1.i = (i32x4v){(int)W20, (int)W21, (int)W30, (int)W31};
    o0 = mfma32x32x16(vc[0], c0.hv, o0);
    o0 = mfma32x32x16(vc[1], c1.hv, o0);
    o1 = mfma32x32x16(vc[2], c0.hv, o1);
    o1 = mfma32x32x16(vc[3], c1.hv, o1);
  };

  bf16x8v ka[4], va[4], kn2[4], vn2[4];
  LDK(jlo_w, ka); LDV(jlo_w, va);
  int it = 0;
  while (it + 2 <= myN) {
    STEP(it, ka, va, kn2, vn2);
    STEP(it + 1, kn2, vn2, ka, va);
    it += 2;
  }
  if (it < myN) STEP(it, ka, va, kn2, vn2);

  // additive merge: wave1 -> LDS, wave0 accumulates and writes out
  if (wid == 1) {
    float* mp = msum + lane * 33;
#pragma unroll
    for (int i = 0; i < 16; ++i) { mp[i] = o0[i]; mp[16 + i] = o1[i]; }
    mp[32] = lrun;
  }
  __syncthreads();
  if (wid == 0) {
    const float* mp = msum + lane * 33;
#pragma unroll
    for (int i = 0; i < 16; ++i) { o0[i] += mp[i]; o1[i] += mp[16 + i]; }
    lrun += mp[32];
    lrun += __shfl_xor(lrun, 32);
    const float inv = 1.0f / lrun;

    const size_t ob = ((size_t)b * S + q0 + l31) * 1024 + h * 64 + hi * 4;
#pragma unroll
    for (int tt = 0; tt < 4; ++tt) {
      uint2 u;
      u.x = pk_bf2(o0[4 * tt] * inv, o0[4 * tt + 1] * inv);
      u.y = pk_bf2(o0[4 * tt + 2] * inv, o0[4 * tt + 3] * inv);
      *reinterpret_cast<uint2*>(&aout[ob + 8 * tt]) = u;
      uint2 v2;
      v2.x = pk_bf2(o1[4 * tt] * inv, o1[4 * tt + 1] * inv);
      v2.y = pk_bf2(o1[4 * tt + 2] * inv, o1[4 * tt + 3] * inv);
      *reinterpret_cast<uint2*>(&aout[ob + 32 + 8 * tt]) = v2;
    }
  }
}

// ---------------- launch ----------------
extern "C" void kernel_launch(void* const* d_in, const int* in_sizes, int n_in,
                              void* d_out, int out_size, void* d_ws, size_t ws_size,
                              hipStream_t stream) {
  (void)in_sizes; (void)n_in; (void)out_size; (void)ws_size;
  const float* x  = (const float*)d_in[0];
  const float* Wq = (const float*)d_in[1];
  const float* bq = (const float*)d_in[2];
  const float* Wk = (const float*)d_in[3];
  const float* bk = (const float*)d_in[4];
  const float* Wv = (const float*)d_in[5];
  const float* bv = (const float*)d_in[6];
  const float* Wo = (const float*)d_in[7];
  const float* bo = (const float*)d_in[8];
  float* out = (float*)d_out;

  char* ws = (char*)d_ws;
  bf16*  xb    = (bf16*)(ws);                    // 8 MB  [4096][1024]
  bf16*  wcat  = (bf16*)(ws + 8388608);          // 6 MB  [3072][1024]
  bf16*  wot   = (bf16*)(ws + 14680064);         // 2 MB  [1024][1024]
  bf16*  qbuf  = (bf16*)(ws + 16777216);         // 8 MB  [B,H,S,64] (pre-scaled)
  bf16*  kbuf  = (bf16*)(ws + 25165824);         // 8 MB  [B,H,S,64]
  bf16*  vtbuf = (bf16*)(ws + 33554432);         // 8 MB  [B,H,64,S]
  bf16*  aoutb = (bf16*)(ws + 41943040);         // 8 MB  [B,S,1024]
  float* bcat  = (float*)(ws + 50331648);        // 12 KB [3072]

  prep_k<<<5132, 256, 0, stream>>>(x, Wq, Wk, Wv, Wo, bq, bk, bv,
                                   xb, wcat, wot, bcat);

  gemm_k<0><<<dim3(32, 24), 256, 0, stream>>>(xb, wcat, bcat, qbuf, kbuf, vtbuf, nullptr);
  attn_k<<<2048, 128, 0, stream>>>(qbuf, kbuf, vtbuf, aoutb);
  gemm_k<1><<<dim3(32, 8), 256, 0, stream>>>(aoutb, wot, bo, nullptr, nullptr, nullptr, out);
}